// Round 7
// baseline (406.256 us; speedup 1.0000x reference)
//
#include <hip/hip_runtime.h>
#include <cstddef>
#include <cstdint>

// Problem constants
#define HH 8
#define FF 512
#define CC 256
#define SS 512
#define BB 64
#define SB (SS*BB)   // 32768

typedef __attribute__((ext_vector_type(4))) float f32x4;
typedef __attribute__((ext_vector_type(8))) short bf16x8;

__device__ __forceinline__ float fast_tanh(float x) {
    float e = __expf(2.0f * x);
    return 1.0f - 2.0f / (e + 1.0f);
}
__device__ __forceinline__ float relu_f(float x) { return fmaxf(x, 0.0f); }

__device__ __forceinline__ unsigned short f2bf(float x) {
    unsigned u = __float_as_uint(x);
    unsigned r = u + 0x7FFFu + ((u >> 16) & 1u);
    return (unsigned short)(r >> 16);
}
__device__ __forceinline__ float bf2f(unsigned short h) {
    return __uint_as_float(((unsigned)h) << 16);
}

// async global->LDS DMA, 16 B per lane. lds base must be wave-uniform;
// data lands at lds + lane*16. gp is per-lane.
__device__ __forceinline__ void async16(void* lds, const void* gp) {
    __builtin_amdgcn_global_load_lds(
        (const __attribute__((address_space(1))) unsigned int*)gp,
        (__attribute__((address_space(3))) unsigned int*)lds,
        16, 0, 0);
}

// ---------------------------------------------------------------------------
// PREP: bid<192: tiled transpose+split of w1/wv ([256][512] hi/lo) and
//       W[h] rows 0..C-1 ([h][256][256] hi/lo).
//       bid 192..195: d4 = relu(d1@w1+b1) (fp32, 64x64 tile each).
// ---------------------------------------------------------------------------
__global__ __launch_bounds__(256) void p_prep(
    const float* __restrict__ w1, const float* __restrict__ wv,
    const float* __restrict__ W, const float* __restrict__ d1,
    const float* __restrict__ b1,
    unsigned short* __restrict__ w1t_hi, unsigned short* __restrict__ w1t_lo,
    unsigned short* __restrict__ wvt_hi, unsigned short* __restrict__ wvt_lo,
    unsigned short* __restrict__ Wt_hi, unsigned short* __restrict__ Wt_lo,
    float* __restrict__ d4)
{
    __shared__ float T[64][65];
    __shared__ float As[16][68];
    __shared__ float Bs[16][68];
    const int tid = threadIdx.x;
    const int bid = blockIdx.x;
    if (bid < 192) {
        const float* src;
        unsigned short *dhi, *dlo;
        int K, kt, nt;
        if (bid < 64) {
            int m = bid >> 5;            // 0: w1, 1: wv
            int t = bid & 31;
            kt = t >> 2; nt = t & 3; K = FF;
            src = m ? wv : w1;
            dhi = m ? wvt_hi : w1t_hi;
            dlo = m ? wvt_lo : w1t_lo;
        } else {
            int t = bid - 64;
            int h = t >> 4; int tt = t & 15;
            kt = tt >> 2; nt = tt & 3; K = CC;
            src = W + (size_t)h * 2 * CC * CC;
            dhi = Wt_hi + (size_t)h * CC * CC;
            dlo = Wt_lo + (size_t)h * CC * CC;
        }
        const int k0 = kt * 64, n0 = nt * 64;
        #pragma unroll
        for (int jj = 0; jj < 4; ++jj) {
            int i = (tid >> 4) + jj * 16;
            int j = (tid & 15) * 4;
            float4 v = *(const float4*)(src + (size_t)(k0 + i) * CC + n0 + j);
            T[i][j] = v.x; T[i][j+1] = v.y; T[i][j+2] = v.z; T[i][j+3] = v.w;
        }
        __syncthreads();
        #pragma unroll
        for (int jj = 0; jj < 4; ++jj) {
            int n = (tid >> 4) + jj * 16;
            int kq = (tid & 15) * 4;
            unsigned short hv[4], lv[4];
            #pragma unroll
            for (int q = 0; q < 4; ++q) {
                float x = T[kq + q][n];
                unsigned short hx = f2bf(x);
                hv[q] = hx; lv[q] = f2bf(x - bf2f(hx));
            }
            size_t o = (size_t)(n0 + n) * K + k0 + kq;
            *(ushort4*)(dhi + o) = *(ushort4*)hv;
            *(ushort4*)(dlo + o) = *(ushort4*)lv;
        }
    } else {
        // d4 tile: 64 rows x 64 cols (n0), fp32 vector GEMM
        const int n0 = (bid - 192) * 64;
        const int tx = tid & 15, ty = tid >> 4;
        const int lm = tid >> 2, lk4 = (tid & 3) * 4;
        const int bk = tid >> 4, bn4 = (tid & 15) * 4;
        float acc[4][4] = {};
        for (int k0 = 0; k0 < FF; k0 += 16) {
            float4 a = *(const float4*)(d1 + (size_t)lm * FF + k0 + lk4);
            As[lk4+0][lm] = a.x; As[lk4+1][lm] = a.y;
            As[lk4+2][lm] = a.z; As[lk4+3][lm] = a.w;
            *(float4*)&Bs[bk][bn4] = *(const float4*)(w1 + (size_t)(k0+bk)*CC + n0 + bn4);
            __syncthreads();
            #pragma unroll
            for (int kk = 0; kk < 16; ++kk) {
                float4 a4 = *(const float4*)&As[kk][ty*4];
                float4 b4 = *(const float4*)&Bs[kk][tx*4];
                float av[4] = {a4.x, a4.y, a4.z, a4.w};
                float bv[4] = {b4.x, b4.y, b4.z, b4.w};
                #pragma unroll
                for (int i = 0; i < 4; ++i)
                    #pragma unroll
                    for (int j = 0; j < 4; ++j)
                        acc[i][j] = fmaf(av[i], bv[j], acc[i][j]);
            }
            __syncthreads();
        }
        #pragma unroll
        for (int i = 0; i < 4; ++i) {
            int row = ty*4 + i;
            #pragma unroll
            for (int j = 0; j < 4; ++j)
                d4[(size_t)row*CC + n0 + tx*4 + j] = relu_f(acc[i][j] + b1[n0 + tx*4 + j]);
        }
    }
}

// ---------------------------------------------------------------------------
// K1: bid<512: 128-row x 256-col MFMA GEMM over d2 (K=512).
//   path = bid>>8: 0 -> d3 = relu(.@w1+b1) split hi/lo, 1 -> tv = tanh(.@wv).
//   B staged via async global_load_lds (no VGPR round trip); A-fragments read
//   direct from global fp32 and split hi/lo in registers.
// bid>=512: e4[h, ntile] fp32 GEMM (d4 @ W[h][C:]).
// ---------------------------------------------------------------------------
__global__ __launch_bounds__(256, 2) void k1_main(
    const float* __restrict__ d2,
    const unsigned short* __restrict__ w1t_hi, const unsigned short* __restrict__ w1t_lo,
    const unsigned short* __restrict__ wvt_hi, const unsigned short* __restrict__ wvt_lo,
    const float* __restrict__ b1,
    const float* __restrict__ d4, const float* __restrict__ W,
    unsigned short* __restrict__ d3_hi, unsigned short* __restrict__ d3_lo,
    unsigned short* __restrict__ tv, float* __restrict__ e4)
{
    __shared__ __align__(16) unsigned short B_hi[256][32];   // 16 KB, DMA dest
    __shared__ __align__(16) unsigned short B_lo[256][32];   // 16 KB, DMA dest
    __shared__ float As[16][68];
    __shared__ float Bs[16][68];

    const int tid = threadIdx.x;
    const int bid = blockIdx.x;

    if (bid >= 512) {
        // ---- e4 path (fp32 vector, tiny) ----
        const int idx = bid - 512;
        const int n0 = (idx & 3) * 64;
        const int h  = idx >> 2;
        const float* Wh = W + ((size_t)h * 2 * CC + CC) * CC;
        const int tx = tid & 15, ty = tid >> 4;
        const int lm = tid >> 2, lk4 = (tid & 3) * 4;
        const int bk = tid >> 4, bn4 = (tid & 15) * 4;
        float acc[4][4] = {};
        for (int k0 = 0; k0 < CC; k0 += 16) {
            float4 a = *(const float4*)(d4 + (size_t)lm * CC + k0 + lk4);
            As[lk4+0][lm] = a.x; As[lk4+1][lm] = a.y;
            As[lk4+2][lm] = a.z; As[lk4+3][lm] = a.w;
            *(float4*)&Bs[bk][bn4] = *(const float4*)(Wh + (size_t)(k0+bk)*CC + n0 + bn4);
            __syncthreads();
            #pragma unroll
            for (int kk = 0; kk < 16; ++kk) {
                float4 a4 = *(const float4*)&As[kk][ty*4];
                float4 b4 = *(const float4*)&Bs[kk][tx*4];
                float av[4] = {a4.x, a4.y, a4.z, a4.w};
                float bv[4] = {b4.x, b4.y, b4.z, b4.w};
                #pragma unroll
                for (int i = 0; i < 4; ++i)
                    #pragma unroll
                    for (int j = 0; j < 4; ++j)
                        acc[i][j] = fmaf(av[i], bv[j], acc[i][j]);
            }
            __syncthreads();
        }
        #pragma unroll
        for (int i = 0; i < 4; ++i) {
            int b = ty*4 + i;
            #pragma unroll
            for (int j = 0; j < 4; ++j)
                e4[((size_t)h*BB + b)*CC + n0 + tx*4 + j] = acc[i][j];
        }
        return;
    }

    // ---- main GEMM path ----
    const int path = bid >> 8;              // 0: w1->d3, 1: wv->tv
    const int r0 = (bid & 255) * 128;
    const int lane = tid & 63, w = tid >> 6;
    const int rowgrp = w & 1, colgrp = w >> 1;
    const int cb = lane & 15, quad = lane >> 4;
    const unsigned short* BH = path ? wvt_hi : w1t_hi;
    const unsigned short* BL = path ? wvt_lo : w1t_lo;

    // DMA source coords: this wave stages rows [w*64, w*64+64) of the B tile.
    const int dn = w * 64 + (lane >> 2);     // + jj*16
    const int dk = (lane & 3) * 8;

    f32x4 acc[4][8];
    f32x4 zero = {0.0f, 0.0f, 0.0f, 0.0f};
    #pragma unroll
    for (int rt = 0; rt < 4; ++rt)
        #pragma unroll
        for (int ct = 0; ct < 8; ++ct) acc[rt][ct] = zero;

    for (int k0 = 0; k0 < FF; k0 += 32) {
        // issue async B staging: 8 x 1KB per wave
        #pragma unroll
        for (int jj = 0; jj < 4; ++jj) {
            const size_t go = (size_t)(dn + jj*16) * FF + k0 + dk;
            async16((char*)B_hi + (w*4 + jj) * 1024, BH + go);
            async16((char*)B_lo + (w*4 + jj) * 1024, BL + go);
        }
        // A-fragments: direct global fp32, split hi/lo in regs
        bf16x8 ahf[4], alf[4];
        #pragma unroll
        for (int rt = 0; rt < 4; ++rt) {
            const float* ap = d2 + (size_t)(r0 + rowgrp*64 + rt*16 + cb) * FF + k0 + quad*8;
            float v[8];
            *(float4*)&v[0] = *(const float4*)ap;
            *(float4*)&v[4] = *(const float4*)(ap + 4);
            #pragma unroll
            for (int j = 0; j < 8; ++j) {
                unsigned short h = f2bf(v[j]);
                ahf[rt][j] = (short)h;
                alf[rt][j] = (short)f2bf(v[j] - bf2f(h));
            }
        }
        __syncthreads();   // drains DMA (vmcnt) + all waves ready
        #pragma unroll
        for (int ct = 0; ct < 8; ++ct) {
            bf16x8 bh = *(bf16x8*)&B_hi[colgrp*128 + ct*16 + cb][quad*8];
            bf16x8 bl = *(bf16x8*)&B_lo[colgrp*128 + ct*16 + cb][quad*8];
            #pragma unroll
            for (int rt = 0; rt < 4; ++rt) {
                acc[rt][ct] = __builtin_amdgcn_mfma_f32_16x16x32_bf16(ahf[rt], bh, acc[rt][ct], 0, 0, 0);
                acc[rt][ct] = __builtin_amdgcn_mfma_f32_16x16x32_bf16(ahf[rt], bl, acc[rt][ct], 0, 0, 0);
                acc[rt][ct] = __builtin_amdgcn_mfma_f32_16x16x32_bf16(alf[rt], bh, acc[rt][ct], 0, 0, 0);
            }
        }
        __syncthreads();   // all reads done before next chunk's DMA lands
    }
    // epilogue. C layout: col = ct*16+cb (+colgrp*128), row = rt*16+quad*4+reg (+rowgrp*64)
    if (path == 0) {
        float bias[8];
        #pragma unroll
        for (int ct = 0; ct < 8; ++ct) bias[ct] = b1[colgrp*128 + ct*16 + cb];
        #pragma unroll
        for (int rt = 0; rt < 4; ++rt) {
            #pragma unroll
            for (int r = 0; r < 4; ++r) {
                int gr = r0 + rowgrp*64 + rt*16 + quad*4 + r;
                #pragma unroll
                for (int ct = 0; ct < 8; ++ct) {
                    int c = colgrp*128 + ct*16 + cb;
                    float val = relu_f(acc[rt][ct][r] + bias[ct]);
                    unsigned short hv = f2bf(val);
                    d3_hi[(size_t)gr * CC + c] = hv;
                    d3_lo[(size_t)gr * CC + c] = f2bf(val - bf2f(hv));
                }
            }
        }
    } else {
        #pragma unroll
        for (int rt = 0; rt < 4; ++rt) {
            #pragma unroll
            for (int r = 0; r < 4; ++r) {
                int gr = r0 + rowgrp*64 + rt*16 + quad*4 + r;
                int s = gr >> 6, b = gr & 63;
                #pragma unroll
                for (int ct = 0; ct < 8; ++ct) {
                    int c = colgrp*128 + ct*16 + cb;
                    tv[((size_t)b * SS + s) * CC + c] = f2bf(fast_tanh(acc[rt][ct][r]));
                }
            }
        }
    }
}

// ---------------------------------------------------------------------------
// K3: atts[h,b,s] = sum_c P[h,c]*tanh((d3@Wt[h])[row,c] + e4[h,b,c]).
// Block: 128 rows (2 s) x 256 cols, one head. B (Wt) via async DMA to LDS;
// A-fragments (d3 hi/lo, already bf16) direct global -> VGPR.
// ---------------------------------------------------------------------------
__global__ __launch_bounds__(256, 2) void k3_atts(
    const unsigned short* __restrict__ d3_hi, const unsigned short* __restrict__ d3_lo,
    const unsigned short* __restrict__ Wt_hi, const unsigned short* __restrict__ Wt_lo,
    const float* __restrict__ e4, const float* __restrict__ P,
    float* __restrict__ atts)
{
    __shared__ __align__(16) unsigned short B_hi[256][32];   // 16 KB
    __shared__ __align__(16) unsigned short B_lo[256][32];   // 16 KB
    __shared__ float red[2][128];

    const int tid = threadIdx.x;
    const int lane = tid & 63, w = tid >> 6;
    const int h = blockIdx.y;
    const int r0 = blockIdx.x * 128;
    const int rowgrp = w & 1, colgrp = w >> 1;
    const int cb = lane & 15, quad = lane >> 4;

    const unsigned short* WhH = Wt_hi + (size_t)h * CC * CC;
    const unsigned short* WhL = Wt_lo + (size_t)h * CC * CC;

    const int dn = w * 64 + (lane >> 2);
    const int dk = (lane & 3) * 8;

    f32x4 acc[4][8];
    f32x4 zero = {0.0f, 0.0f, 0.0f, 0.0f};
    #pragma unroll
    for (int rt = 0; rt < 4; ++rt)
        #pragma unroll
        for (int ct = 0; ct < 8; ++ct) acc[rt][ct] = zero;

    for (int k0 = 0; k0 < CC; k0 += 32) {
        #pragma unroll
        for (int jj = 0; jj < 4; ++jj) {
            const size_t go = (size_t)(dn + jj*16) * CC + k0 + dk;
            async16((char*)B_hi + (w*4 + jj) * 1024, WhH + go);
            async16((char*)B_lo + (w*4 + jj) * 1024, WhL + go);
        }
        bf16x8 ahf[4], alf[4];
        #pragma unroll
        for (int rt = 0; rt < 4; ++rt) {
            const size_t ao = (size_t)(r0 + rowgrp*64 + rt*16 + cb) * CC + k0 + quad*8;
            ahf[rt] = *(const bf16x8*)(d3_hi + ao);
            alf[rt] = *(const bf16x8*)(d3_lo + ao);
        }
        __syncthreads();
        #pragma unroll
        for (int ct = 0; ct < 8; ++ct) {
            bf16x8 bh = *(bf16x8*)&B_hi[colgrp*128 + ct*16 + cb][quad*8];
            bf16x8 bl = *(bf16x8*)&B_lo[colgrp*128 + ct*16 + cb][quad*8];
            #pragma unroll
            for (int rt = 0; rt < 4; ++rt) {
                acc[rt][ct] = __builtin_amdgcn_mfma_f32_16x16x32_bf16(ahf[rt], bh, acc[rt][ct], 0, 0, 0);
                acc[rt][ct] = __builtin_amdgcn_mfma_f32_16x16x32_bf16(ahf[rt], bl, acc[rt][ct], 0, 0, 0);
                acc[rt][ct] = __builtin_amdgcn_mfma_f32_16x16x32_bf16(alf[rt], bh, acc[rt][ct], 0, 0, 0);
            }
        }
        __syncthreads();
    }
    // epilogue: tanh + P-dot over this wave's 128 cols, then reduce
    float Pv[8];
    #pragma unroll
    for (int ct = 0; ct < 8; ++ct) Pv[ct] = P[(size_t)h * CC + colgrp*128 + ct*16 + cb];
    #pragma unroll
    for (int rt = 0; rt < 4; ++rt) {
        #pragma unroll
        for (int r = 0; r < 4; ++r) {
            int b = rt*16 + quad*4 + r;     // batch index (mod 64)
            const float* e4p = e4 + ((size_t)h * BB + b) * CC + colgrp*128 + cb;
            float part = 0.0f;
            #pragma unroll
            for (int ct = 0; ct < 8; ++ct) {
                float u = acc[rt][ct][r] + e4p[ct*16];
                part = fmaf(Pv[ct], fast_tanh(u), part);
            }
            part += __shfl_xor(part, 1); part += __shfl_xor(part, 2);
            part += __shfl_xor(part, 4); part += __shfl_xor(part, 8);
            if (cb == 0) red[colgrp][rowgrp*64 + b] = part;
        }
    }
    __syncthreads();
    if (tid < 128) {
        float v = red[0][tid] + red[1][tid];
        int gr = r0 + tid;
        int s = gr >> 6, b = gr & 63;
        atts[((size_t)h * BB + b) * SS + s] = v;
    }
}

// ---------------------------------------------------------------------------
// K456: per b: softmax over s (8 heads) + vs = scores.tv + out = relu(vs@wcc+bcc)
// ---------------------------------------------------------------------------
__global__ __launch_bounds__(256) void k456_out(
    const float* __restrict__ atts, const unsigned short* __restrict__ tv,
    const float* __restrict__ wcc, const float* __restrict__ bcc,
    float* __restrict__ out)
{
    __shared__ float sc[HH][SS];       // 16 KB
    __shared__ float red[4][2048];     // 32 KB
    const int b = blockIdx.x;
    const int tid = threadIdx.x;
    const int lane = tid & 63, w = tid >> 6;

    for (int i = tid; i < HH*SS; i += 256) {
        int h = i >> 9, s = i & 511;
        sc[h][s] = atts[((size_t)h*BB + b)*SS + s];
    }
    __syncthreads();
    // softmax: wave w handles heads 2w, 2w+1
    #pragma unroll
    for (int t = 0; t < 2; ++t) {
        int hh = w*2 + t;
        float x[8];
        #pragma unroll
        for (int j = 0; j < 8; ++j) x[j] = sc[hh][j*64 + lane];
        float m = x[0];
        #pragma unroll
        for (int j = 1; j < 8; ++j) m = fmaxf(m, x[j]);
        #pragma unroll
        for (int d = 1; d < 64; d <<= 1) m = fmaxf(m, __shfl_xor(m, d));
        float sum = 0.0f;
        #pragma unroll
        for (int j = 0; j < 8; ++j) { x[j] = __expf(x[j] - m); sum += x[j]; }
        #pragma unroll
        for (int d = 1; d < 64; d <<= 1) sum += __shfl_xor(sum, d);
        float inv = 1.0f / sum;
        #pragma unroll
        for (int j = 0; j < 8; ++j) sc[hh][j*64 + lane] = x[j] * inv;
    }
    __syncthreads();
    // vs: stripe = s-range of 128, each lane owns 4 c
    {
        const int cl = tid & 63, stripe = tid >> 6;
        const int c0 = cl * 4;
        const unsigned short* tvb = tv + ((size_t)b * SS + stripe * 128) * CC + c0;
        float acc[HH][4] = {};
        for (int si = 0; si < 128; ++si) {
            uint2 u = *(const uint2*)(tvb + (size_t)si * CC);
            float x0 = bf2f((unsigned short)(u.x));
            float x1 = bf2f((unsigned short)(u.x >> 16));
            float x2 = bf2f((unsigned short)(u.y));
            float x3 = bf2f((unsigned short)(u.y >> 16));
            int s = stripe * 128 + si;
            #pragma unroll
            for (int h = 0; h < HH; ++h) {
                float wgt = sc[h][s];
                acc[h][0] = fmaf(wgt, x0, acc[h][0]);
                acc[h][1] = fmaf(wgt, x1, acc[h][1]);
                acc[h][2] = fmaf(wgt, x2, acc[h][2]);
                acc[h][3] = fmaf(wgt, x3, acc[h][3]);
            }
        }
        #pragma unroll
        for (int h = 0; h < HH; ++h)
            #pragma unroll
            for (int j = 0; j < 4; ++j)
                red[stripe][h*256 + c0 + j] = acc[h][j];
    }
    __syncthreads();
    for (int i = tid; i < 2048; i += 256)
        red[0][i] = red[0][i] + red[1][i] + red[2][i] + red[3][i];
    __syncthreads();
    // out: 2 threads per output column
    {
        const int n = tid & 127, half = tid >> 7;
        float o = 0.0f;
        const int kbase = half * 1024;
        for (int k = 0; k < 1024; ++k)
            o = fmaf(red[0][kbase + k], wcc[(size_t)(kbase + k) * 128 + n], o);
        float* r2 = &sc[0][0];
        r2[half * 128 + n] = o;
    }
    __syncthreads();
    if (tid < 128)
        out[(size_t)b * 128 + tid] = relu_f(sc[0][tid] + sc[0][128 + tid] + bcc[tid]);
}

// ---------------------------------------------------------------------------
extern "C" void kernel_launch(void* const* d_in, const int* in_sizes, int n_in,
                              void* d_out, int out_size, void* d_ws, size_t ws_size,
                              hipStream_t stream)
{
    (void)in_sizes; (void)n_in; (void)out_size; (void)ws_size;
    const float* d1  = (const float*)d_in[0];
    const float* d2  = (const float*)d_in[1];
    const float* w1  = (const float*)d_in[2];
    const float* b1  = (const float*)d_in[3];
    const float* W   = (const float*)d_in[4];
    const float* P   = (const float*)d_in[5];
    const float* wv  = (const float*)d_in[6];
    const float* wcc = (const float*)d_in[7];
    const float* bcc = (const float*)d_in[8];
    float* out = (float*)d_out;

    char* p = (char*)d_ws;
    unsigned short* d3_hi = (unsigned short*)p;  p += (size_t)SB * CC * 2;
    unsigned short* d3_lo = (unsigned short*)p;  p += (size_t)SB * CC * 2;
    unsigned short* tv    = (unsigned short*)p;  p += (size_t)BB * SS * CC * 2;
    unsigned short* w1t_hi = (unsigned short*)p; p += (size_t)CC * FF * 2;
    unsigned short* w1t_lo = (unsigned short*)p; p += (size_t)CC * FF * 2;
    unsigned short* wvt_hi = (unsigned short*)p; p += (size_t)CC * FF * 2;
    unsigned short* wvt_lo = (unsigned short*)p; p += (size_t)CC * FF * 2;
    unsigned short* Wt_hi  = (unsigned short*)p; p += (size_t)HH * CC * CC * 2;
    unsigned short* Wt_lo  = (unsigned short*)p; p += (size_t)HH * CC * CC * 2;
    float* d4   = (float*)p;  p += (size_t)BB * CC * 4;
    float* e4   = (float*)p;  p += (size_t)HH * BB * CC * 4;
    float* atts = (float*)p;  p += (size_t)HH * BB * SS * 4;

    p_prep   <<<dim3(196),       256, 0, stream>>>(w1, wv, W, d1, b1,
                  w1t_hi, w1t_lo, wvt_hi, wvt_lo, Wt_hi, Wt_lo, d4);
    k1_main  <<<dim3(544),       256, 0, stream>>>(d2, w1t_hi, w1t_lo,
                  wvt_hi, wvt_lo, b1, d4, W, d3_hi, d3_lo, tv, e4);
    k3_atts  <<<dim3(256, HH),   256, 0, stream>>>(d3_hi, d3_lo, Wt_hi, Wt_lo,
                  e4, P, atts);
    k456_out <<<dim3(BB),        256, 0, stream>>>(atts, tv, wcc, bcc, out);
}

// Round 8
// 379.422 us; speedup vs baseline: 1.0707x; 1.0707x over previous
//
#include <hip/hip_runtime.h>
#include <cstddef>
#include <cstdint>

// Problem constants
#define HH 8
#define FF 512
#define CC 256
#define SS 512
#define BB 64
#define SB (SS*BB)   // 32768

typedef __attribute__((ext_vector_type(4))) float f32x4;
typedef __attribute__((ext_vector_type(8))) short bf16x8;

__device__ __forceinline__ float fast_tanh(float x) {
    float e = __expf(2.0f * x);
    return 1.0f - 2.0f / (e + 1.0f);
}
__device__ __forceinline__ float relu_f(float x) { return fmaxf(x, 0.0f); }

__device__ __forceinline__ unsigned short f2bf(float x) {
    unsigned u = __float_as_uint(x);
    unsigned r = u + 0x7FFFu + ((u >> 16) & 1u);
    return (unsigned short)(r >> 16);
}
__device__ __forceinline__ float bf2f(unsigned short h) {
    return __uint_as_float(((unsigned)h) << 16);
}

// ---------------------------------------------------------------------------
// PREP: bid<192: tiled transpose+split of w1/wv ([256][512] hi/lo) and
//       W[h] rows 0..C-1 ([h][256][256] hi/lo).
//       bid 192..195: d4 = relu(d1@w1+b1) (fp32, 64x64 tile each).
//       bid 196..451: zero atts (k3 accumulates into it atomically).
// ---------------------------------------------------------------------------
__global__ __launch_bounds__(256) void p_prep(
    const float* __restrict__ w1, const float* __restrict__ wv,
    const float* __restrict__ W, const float* __restrict__ d1,
    const float* __restrict__ b1,
    unsigned short* __restrict__ w1t_hi, unsigned short* __restrict__ w1t_lo,
    unsigned short* __restrict__ wvt_hi, unsigned short* __restrict__ wvt_lo,
    unsigned short* __restrict__ Wt_hi, unsigned short* __restrict__ Wt_lo,
    float* __restrict__ d4, float* __restrict__ atts)
{
    __shared__ float T[64][65];
    __shared__ float As[16][68];
    __shared__ float Bs[16][68];
    const int tid = threadIdx.x;
    const int bid = blockIdx.x;
    if (bid >= 196) {
        // zero atts: 256 blocks x 256 thr x 4 floats = 262144
        f32x4 z = {0.0f, 0.0f, 0.0f, 0.0f};
        *(f32x4*)(atts + (size_t)(bid - 196) * 1024 + tid * 4) = z;
        return;
    }
    if (bid < 192) {
        const float* src;
        unsigned short *dhi, *dlo;
        int K, kt, nt;
        if (bid < 64) {
            int m = bid >> 5;            // 0: w1, 1: wv
            int t = bid & 31;
            kt = t >> 2; nt = t & 3; K = FF;
            src = m ? wv : w1;
            dhi = m ? wvt_hi : w1t_hi;
            dlo = m ? wvt_lo : w1t_lo;
        } else {
            int t = bid - 64;
            int h = t >> 4; int tt = t & 15;
            kt = tt >> 2; nt = tt & 3; K = CC;
            src = W + (size_t)h * 2 * CC * CC;
            dhi = Wt_hi + (size_t)h * CC * CC;
            dlo = Wt_lo + (size_t)h * CC * CC;
        }
        const int k0 = kt * 64, n0 = nt * 64;
        #pragma unroll
        for (int jj = 0; jj < 4; ++jj) {
            int i = (tid >> 4) + jj * 16;
            int j = (tid & 15) * 4;
            float4 v = *(const float4*)(src + (size_t)(k0 + i) * CC + n0 + j);
            T[i][j] = v.x; T[i][j+1] = v.y; T[i][j+2] = v.z; T[i][j+3] = v.w;
        }
        __syncthreads();
        #pragma unroll
        for (int jj = 0; jj < 4; ++jj) {
            int n = (tid >> 4) + jj * 16;
            int kq = (tid & 15) * 4;
            unsigned short hv[4], lv[4];
            #pragma unroll
            for (int q = 0; q < 4; ++q) {
                float x = T[kq + q][n];
                unsigned short hx = f2bf(x);
                hv[q] = hx; lv[q] = f2bf(x - bf2f(hx));
            }
            size_t o = (size_t)(n0 + n) * K + k0 + kq;
            *(ushort4*)(dhi + o) = *(ushort4*)hv;
            *(ushort4*)(dlo + o) = *(ushort4*)lv;
        }
    } else {
        // d4 tile: 64 rows x 64 cols (n0), fp32 vector GEMM
        const int n0 = (bid - 192) * 64;
        const int tx = tid & 15, ty = tid >> 4;
        const int lm = tid >> 2, lk4 = (tid & 3) * 4;
        const int bk = tid >> 4, bn4 = (tid & 15) * 4;
        float acc[4][4] = {};
        for (int k0 = 0; k0 < FF; k0 += 16) {
            float4 a = *(const float4*)(d1 + (size_t)lm * FF + k0 + lk4);
            As[lk4+0][lm] = a.x; As[lk4+1][lm] = a.y;
            As[lk4+2][lm] = a.z; As[lk4+3][lm] = a.w;
            *(float4*)&Bs[bk][bn4] = *(const float4*)(w1 + (size_t)(k0+bk)*CC + n0 + bn4);
            __syncthreads();
            #pragma unroll
            for (int kk = 0; kk < 16; ++kk) {
                float4 a4 = *(const float4*)&As[kk][ty*4];
                float4 b4 = *(const float4*)&Bs[kk][tx*4];
                float av[4] = {a4.x, a4.y, a4.z, a4.w};
                float bv[4] = {b4.x, b4.y, b4.z, b4.w};
                #pragma unroll
                for (int i = 0; i < 4; ++i)
                    #pragma unroll
                    for (int j = 0; j < 4; ++j)
                        acc[i][j] = fmaf(av[i], bv[j], acc[i][j]);
            }
            __syncthreads();
        }
        #pragma unroll
        for (int i = 0; i < 4; ++i) {
            int row = ty*4 + i;
            #pragma unroll
            for (int j = 0; j < 4; ++j)
                d4[(size_t)row*CC + n0 + tx*4 + j] = relu_f(acc[i][j] + b1[n0 + tx*4 + j]);
        }
    }
}

// ---------------------------------------------------------------------------
// K1: bid<1024: 128x128 MFMA GEMM tile over d2 (K=512).
//   rowtile = bid&255, colhalf = (bid>>8)&1, path = bid>>9
//   path 0 -> d3 = relu(.@w1+b1) split hi/lo;  path 1 -> tv = tanh(.@wv).
//   4 waves in 2x2 (wave tile 64x64, acc[4][4] = 64 AGPR -> 3+ waves/SIMD).
// bid>=1024: e4[h, ntile] fp32 GEMM (d4 @ W[h][C:]), LDS aliased.
// ---------------------------------------------------------------------------
__global__ __launch_bounds__(256, 3) void k1_main(
    const float* __restrict__ d2,
    const unsigned short* __restrict__ w1t_hi, const unsigned short* __restrict__ w1t_lo,
    const unsigned short* __restrict__ wvt_hi, const unsigned short* __restrict__ wvt_lo,
    const float* __restrict__ b1,
    const float* __restrict__ d4, const float* __restrict__ W,
    unsigned short* __restrict__ d3_hi, unsigned short* __restrict__ d3_lo,
    unsigned short* __restrict__ tv, float* __restrict__ e4)
{
    __shared__ __align__(16) unsigned short A_hi[128][40];   // 10 KB
    __shared__ __align__(16) unsigned short A_lo[128][40];
    __shared__ __align__(16) unsigned short B_hi[128][40];
    __shared__ __align__(16) unsigned short B_lo[128][40];

    const int tid = threadIdx.x;
    const int bid = blockIdx.x;

    if (bid >= 1024) {
        // ---- e4 path (fp32 vector, tiny). Alias LDS. ----
        float (*As)[68] = (float(*)[68])&A_hi[0][0];
        float (*Bs)[68] = (float(*)[68])&A_lo[0][0];
        const int idx = bid - 1024;
        const int n0 = (idx & 3) * 64;
        const int h  = idx >> 2;
        const float* Wh = W + ((size_t)h * 2 * CC + CC) * CC;
        const int tx = tid & 15, ty = tid >> 4;
        const int lm = tid >> 2, lk4 = (tid & 3) * 4;
        const int bk = tid >> 4, bn4 = (tid & 15) * 4;
        float acc[4][4] = {};
        for (int k0 = 0; k0 < CC; k0 += 16) {
            float4 a = *(const float4*)(d4 + (size_t)lm * CC + k0 + lk4);
            As[lk4+0][lm] = a.x; As[lk4+1][lm] = a.y;
            As[lk4+2][lm] = a.z; As[lk4+3][lm] = a.w;
            *(float4*)&Bs[bk][bn4] = *(const float4*)(Wh + (size_t)(k0+bk)*CC + n0 + bn4);
            __syncthreads();
            #pragma unroll
            for (int kk = 0; kk < 16; ++kk) {
                float4 a4 = *(const float4*)&As[kk][ty*4];
                float4 b4 = *(const float4*)&Bs[kk][tx*4];
                float av[4] = {a4.x, a4.y, a4.z, a4.w};
                float bv[4] = {b4.x, b4.y, b4.z, b4.w};
                #pragma unroll
                for (int i = 0; i < 4; ++i)
                    #pragma unroll
                    for (int j = 0; j < 4; ++j)
                        acc[i][j] = fmaf(av[i], bv[j], acc[i][j]);
            }
            __syncthreads();
        }
        #pragma unroll
        for (int i = 0; i < 4; ++i) {
            int b = ty*4 + i;
            #pragma unroll
            for (int j = 0; j < 4; ++j)
                e4[((size_t)h*BB + b)*CC + n0 + tx*4 + j] = acc[i][j];
        }
        return;
    }

    // ---- main GEMM path ----
    const int rowtile = bid & 255;
    const int colhalf = (bid >> 8) & 1;
    const int path    = bid >> 9;           // 0: w1->d3, 1: wv->tv
    const int r0 = rowtile * 128;
    const int n0 = colhalf * 128;
    const int lane = tid & 63, w = tid >> 6;
    const int rowgrp = w & 1, colgrp = w >> 1;
    const int cb = lane & 15, quad = lane >> 4;
    const unsigned short* BH = path ? wvt_hi : w1t_hi;
    const unsigned short* BL = path ? wvt_lo : w1t_lo;

    const int srow = tid >> 1;              // 0..127
    const int sk   = (tid & 1) * 16;        // 0 or 16

    f32x4 acc[4][4];
    f32x4 zero = {0.0f, 0.0f, 0.0f, 0.0f};
    #pragma unroll
    for (int rt = 0; rt < 4; ++rt)
        #pragma unroll
        for (int ct = 0; ct < 4; ++ct) acc[rt][ct] = zero;

    for (int k0 = 0; k0 < FF; k0 += 32) {
        // stage A: 128 rows x 32 k, fp32 -> hi/lo split (16 floats/thread)
        {
            const float* src = d2 + (size_t)(r0 + srow) * FF + k0 + sk;
            float v[16];
            *(float4*)&v[0]  = *(const float4*)(src);
            *(float4*)&v[4]  = *(const float4*)(src + 4);
            *(float4*)&v[8]  = *(const float4*)(src + 8);
            *(float4*)&v[12] = *(const float4*)(src + 12);
            bf16x8 vh0, vh1, vl0, vl1;
            #pragma unroll
            for (int j = 0; j < 8; ++j) {
                unsigned short h = f2bf(v[j]);
                vh0[j] = (short)h; vl0[j] = (short)f2bf(v[j] - bf2f(h));
                unsigned short h2 = f2bf(v[j+8]);
                vh1[j] = (short)h2; vl1[j] = (short)f2bf(v[j+8] - bf2f(h2));
            }
            *(bf16x8*)&A_hi[srow][sk]     = vh0;
            *(bf16x8*)&A_hi[srow][sk + 8] = vh1;
            *(bf16x8*)&A_lo[srow][sk]     = vl0;
            *(bf16x8*)&A_lo[srow][sk + 8] = vl1;
        }
        // stage B: 128 n x 32 k (this col-half)
        {
            const size_t go = (size_t)(n0 + srow) * FF + k0 + sk;
            *(bf16x8*)&B_hi[srow][sk]     = *(const bf16x8*)(BH + go);
            *(bf16x8*)&B_hi[srow][sk + 8] = *(const bf16x8*)(BH + go + 8);
            *(bf16x8*)&B_lo[srow][sk]     = *(const bf16x8*)(BL + go);
            *(bf16x8*)&B_lo[srow][sk + 8] = *(const bf16x8*)(BL + go + 8);
        }
        __syncthreads();
        bf16x8 ahf[4], alf[4];
        #pragma unroll
        for (int rt = 0; rt < 4; ++rt) {
            ahf[rt] = *(bf16x8*)&A_hi[rowgrp*64 + rt*16 + cb][quad*8];
            alf[rt] = *(bf16x8*)&A_lo[rowgrp*64 + rt*16 + cb][quad*8];
        }
        #pragma unroll
        for (int ct = 0; ct < 4; ++ct) {
            bf16x8 bh = *(bf16x8*)&B_hi[colgrp*64 + ct*16 + cb][quad*8];
            bf16x8 bl = *(bf16x8*)&B_lo[colgrp*64 + ct*16 + cb][quad*8];
            #pragma unroll
            for (int rt = 0; rt < 4; ++rt) {
                acc[rt][ct] = __builtin_amdgcn_mfma_f32_16x16x32_bf16(ahf[rt], bh, acc[rt][ct], 0, 0, 0);
                acc[rt][ct] = __builtin_amdgcn_mfma_f32_16x16x32_bf16(ahf[rt], bl, acc[rt][ct], 0, 0, 0);
                acc[rt][ct] = __builtin_amdgcn_mfma_f32_16x16x32_bf16(alf[rt], bh, acc[rt][ct], 0, 0, 0);
            }
        }
        __syncthreads();
    }
    // epilogue. col = n0 + colgrp*64 + ct*16 + cb; row = r0 + rowgrp*64 + rt*16 + quad*4 + r
    if (path == 0) {
        float bias[4];
        #pragma unroll
        for (int ct = 0; ct < 4; ++ct) bias[ct] = b1[n0 + colgrp*64 + ct*16 + cb];
        #pragma unroll
        for (int rt = 0; rt < 4; ++rt) {
            #pragma unroll
            for (int r = 0; r < 4; ++r) {
                int gr = r0 + rowgrp*64 + rt*16 + quad*4 + r;
                #pragma unroll
                for (int ct = 0; ct < 4; ++ct) {
                    int c = n0 + colgrp*64 + ct*16 + cb;
                    float val = relu_f(acc[rt][ct][r] + bias[ct]);
                    unsigned short hv = f2bf(val);
                    d3_hi[(size_t)gr * CC + c] = hv;
                    d3_lo[(size_t)gr * CC + c] = f2bf(val - bf2f(hv));
                }
            }
        }
    } else {
        #pragma unroll
        for (int rt = 0; rt < 4; ++rt) {
            #pragma unroll
            for (int r = 0; r < 4; ++r) {
                int gr = r0 + rowgrp*64 + rt*16 + quad*4 + r;
                int s = gr >> 6, b = gr & 63;
                #pragma unroll
                for (int ct = 0; ct < 4; ++ct) {
                    int c = n0 + colgrp*64 + ct*16 + cb;
                    tv[((size_t)b * SS + s) * CC + c] = f2bf(fast_tanh(acc[rt][ct][r]));
                }
            }
        }
    }
}

// ---------------------------------------------------------------------------
// K3: partial atts[h,b,s] += sum_{c in half} P[h,c]*tanh((d3@Wt[h])[row,c] + e4)
// Block: 128 rows x 128 cols (col-half), one head. atomicAdd combine.
// blockIdx.x: rowtile + 256*colhalf; blockIdx.y: head.
// ---------------------------------------------------------------------------
__global__ __launch_bounds__(256, 3) void k3_atts(
    const unsigned short* __restrict__ d3_hi, const unsigned short* __restrict__ d3_lo,
    const unsigned short* __restrict__ Wt_hi, const unsigned short* __restrict__ Wt_lo,
    const float* __restrict__ e4, const float* __restrict__ P,
    float* __restrict__ atts)
{
    __shared__ __align__(16) unsigned short A_hi[128][40];
    __shared__ __align__(16) unsigned short A_lo[128][40];
    __shared__ __align__(16) unsigned short B_hi[128][40];
    __shared__ __align__(16) unsigned short B_lo[128][40];
    __shared__ float red[2][128];

    const int tid = threadIdx.x;
    const int lane = tid & 63, w = tid >> 6;
    const int h = blockIdx.y;
    const int rowtile = blockIdx.x & 255;
    const int colhalf = blockIdx.x >> 8;
    const int r0 = rowtile * 128;
    const int n0 = colhalf * 128;
    const int rowgrp = w & 1, colgrp = w >> 1;
    const int cb = lane & 15, quad = lane >> 4;

    const unsigned short* WhH = Wt_hi + (size_t)h * CC * CC;
    const unsigned short* WhL = Wt_lo + (size_t)h * CC * CC;

    const int srow = tid >> 1;
    const int sk   = (tid & 1) * 16;

    f32x4 acc[4][4];
    f32x4 zero = {0.0f, 0.0f, 0.0f, 0.0f};
    #pragma unroll
    for (int rt = 0; rt < 4; ++rt)
        #pragma unroll
        for (int ct = 0; ct < 4; ++ct) acc[rt][ct] = zero;

    for (int k0 = 0; k0 < CC; k0 += 32) {
        {
            const size_t ao = (size_t)(r0 + srow) * CC + k0 + sk;
            *(bf16x8*)&A_hi[srow][sk]     = *(const bf16x8*)(d3_hi + ao);
            *(bf16x8*)&A_hi[srow][sk + 8] = *(const bf16x8*)(d3_hi + ao + 8);
            *(bf16x8*)&A_lo[srow][sk]     = *(const bf16x8*)(d3_lo + ao);
            *(bf16x8*)&A_lo[srow][sk + 8] = *(const bf16x8*)(d3_lo + ao + 8);
            const size_t go = (size_t)(n0 + srow) * CC + k0 + sk;
            *(bf16x8*)&B_hi[srow][sk]     = *(const bf16x8*)(WhH + go);
            *(bf16x8*)&B_hi[srow][sk + 8] = *(const bf16x8*)(WhH + go + 8);
            *(bf16x8*)&B_lo[srow][sk]     = *(const bf16x8*)(WhL + go);
            *(bf16x8*)&B_lo[srow][sk + 8] = *(const bf16x8*)(WhL + go + 8);
        }
        __syncthreads();
        bf16x8 ahf[4], alf[4];
        #pragma unroll
        for (int rt = 0; rt < 4; ++rt) {
            ahf[rt] = *(bf16x8*)&A_hi[rowgrp*64 + rt*16 + cb][quad*8];
            alf[rt] = *(bf16x8*)&A_lo[rowgrp*64 + rt*16 + cb][quad*8];
        }
        #pragma unroll
        for (int ct = 0; ct < 4; ++ct) {
            bf16x8 bh = *(bf16x8*)&B_hi[colgrp*64 + ct*16 + cb][quad*8];
            bf16x8 bl = *(bf16x8*)&B_lo[colgrp*64 + ct*16 + cb][quad*8];
            #pragma unroll
            for (int rt = 0; rt < 4; ++rt) {
                acc[rt][ct] = __builtin_amdgcn_mfma_f32_16x16x32_bf16(ahf[rt], bh, acc[rt][ct], 0, 0, 0);
                acc[rt][ct] = __builtin_amdgcn_mfma_f32_16x16x32_bf16(ahf[rt], bl, acc[rt][ct], 0, 0, 0);
                acc[rt][ct] = __builtin_amdgcn_mfma_f32_16x16x32_bf16(alf[rt], bh, acc[rt][ct], 0, 0, 0);
            }
        }
        __syncthreads();
    }
    // epilogue: tanh + P-dot over this wave's 64 cols; rows are b (mod 64)
    float Pv[4];
    #pragma unroll
    for (int ct = 0; ct < 4; ++ct) Pv[ct] = P[(size_t)h * CC + n0 + colgrp*64 + ct*16 + cb];
    #pragma unroll
    for (int rt = 0; rt < 4; ++rt) {
        #pragma unroll
        for (int r = 0; r < 4; ++r) {
            int lrow = rt*16 + quad*4 + r;          // 0..63 within rowgrp
            int b = lrow;                           // (gr & 63) == lrow
            const float* e4p = e4 + ((size_t)h * BB + b) * CC + n0 + colgrp*64 + cb;
            float part = 0.0f;
            #pragma unroll
            for (int ct = 0; ct < 4; ++ct) {
                float u = acc[rt][ct][r] + e4p[ct*16];
                part = fmaf(Pv[ct], fast_tanh(u), part);
            }
            part += __shfl_xor(part, 1); part += __shfl_xor(part, 2);
            part += __shfl_xor(part, 4); part += __shfl_xor(part, 8);
            if (cb == 0) red[colgrp][rowgrp*64 + lrow] = part;
        }
    }
    __syncthreads();
    if (tid < 128) {
        float v = red[0][tid] + red[1][tid];
        int gr = r0 + tid;
        int s = gr >> 6, b = gr & 63;
        atomicAdd(&atts[((size_t)h * BB + b) * SS + s], v);
    }
}

// ---------------------------------------------------------------------------
// K456: per b (512 thr): softmax over s (8 heads) + vs = scores.tv +
//       out = relu(vs@wcc+bcc)
// ---------------------------------------------------------------------------
__global__ __launch_bounds__(512) void k456_out(
    const float* __restrict__ atts, const unsigned short* __restrict__ tv,
    const float* __restrict__ wcc, const float* __restrict__ bcc,
    float* __restrict__ out)
{
    __shared__ float sc[HH][SS];       // 16 KB
    __shared__ float red[8][2048];     // 64 KB
    const int b = blockIdx.x;
    const int tid = threadIdx.x;
    const int lane = tid & 63, w = tid >> 6;

    for (int i = tid; i < HH*SS; i += 512) {
        int h = i >> 9, s = i & 511;
        sc[h][s] = atts[((size_t)h*BB + b)*SS + s];
    }
    __syncthreads();
    // softmax: wave w handles head w
    {
        float x[8];
        #pragma unroll
        for (int j = 0; j < 8; ++j) x[j] = sc[w][j*64 + lane];
        float m = x[0];
        #pragma unroll
        for (int j = 1; j < 8; ++j) m = fmaxf(m, x[j]);
        #pragma unroll
        for (int d = 1; d < 64; d <<= 1) m = fmaxf(m, __shfl_xor(m, d));
        float sum = 0.0f;
        #pragma unroll
        for (int j = 0; j < 8; ++j) { x[j] = __expf(x[j] - m); sum += x[j]; }
        #pragma unroll
        for (int d = 1; d < 64; d <<= 1) sum += __shfl_xor(sum, d);
        float inv = 1.0f / sum;
        #pragma unroll
        for (int j = 0; j < 8; ++j) sc[w][j*64 + lane] = x[j] * inv;
    }
    __syncthreads();
    // vs: stripe = s-range of 64, each lane owns 4 c
    {
        const int cl = tid & 63, stripe = tid >> 6;
        const int c0 = cl * 4;
        const unsigned short* tvb = tv + ((size_t)b * SS + stripe * 64) * CC + c0;
        float acc[HH][4] = {};
        for (int si = 0; si < 64; ++si) {
            uint2 u = *(const uint2*)(tvb + (size_t)si * CC);
            float x0 = bf2f((unsigned short)(u.x));
            float x1 = bf2f((unsigned short)(u.x >> 16));
            float x2 = bf2f((unsigned short)(u.y));
            float x3 = bf2f((unsigned short)(u.y >> 16));
            int s = stripe * 64 + si;
            #pragma unroll
            for (int h = 0; h < HH; ++h) {
                float wgt = sc[h][s];
                acc[h][0] = fmaf(wgt, x0, acc[h][0]);
                acc[h][1] = fmaf(wgt, x1, acc[h][1]);
                acc[h][2] = fmaf(wgt, x2, acc[h][2]);
                acc[h][3] = fmaf(wgt, x3, acc[h][3]);
            }
        }
        #pragma unroll
        for (int h = 0; h < HH; ++h)
            #pragma unroll
            for (int j = 0; j < 4; ++j)
                red[stripe][h*256 + c0 + j] = acc[h][j];
    }
    __syncthreads();
    for (int i = tid; i < 2048; i += 512) {
        float v = red[0][i];
        #pragma unroll
        for (int st = 1; st < 8; ++st) v += red[st][i];
        red[0][i] = v;
    }
    __syncthreads();
    // out: 4 threads per output column
    {
        const int n = tid & 127, q = tid >> 7;
        float o = 0.0f;
        const int kbase = q * 512;
        for (int k = 0; k < 512; ++k)
            o = fmaf(red[0][kbase + k], wcc[(size_t)(kbase + k) * 128 + n], o);
        float* r2 = &sc[0][0];
        r2[q * 128 + n] = o;
    }
    __syncthreads();
    if (tid < 128) {
        float* r2 = &sc[0][0];
        out[(size_t)b * 128 + tid] =
            relu_f(r2[tid] + r2[128 + tid] + r2[256 + tid] + r2[384 + tid] + bcc[tid]);
    }
}

// ---------------------------------------------------------------------------
extern "C" void kernel_launch(void* const* d_in, const int* in_sizes, int n_in,
                              void* d_out, int out_size, void* d_ws, size_t ws_size,
                              hipStream_t stream)
{
    (void)in_sizes; (void)n_in; (void)out_size; (void)ws_size;
    const float* d1  = (const float*)d_in[0];
    const float* d2  = (const float*)d_in[1];
    const float* w1  = (const float*)d_in[2];
    const float* b1  = (const float*)d_in[3];
    const float* W   = (const float*)d_in[4];
    const float* P   = (const float*)d_in[5];
    const float* wv  = (const float*)d_in[6];
    const float* wcc = (const float*)d_in[7];
    const float* bcc = (const float*)d_in[8];
    float* out = (float*)d_out;

    char* p = (char*)d_ws;
    unsigned short* d3_hi = (unsigned short*)p;  p += (size_t)SB * CC * 2;
    unsigned short* d3_lo = (unsigned short*)p;  p += (size_t)SB * CC * 2;
    unsigned short* tv    = (unsigned short*)p;  p += (size_t)BB * SS * CC * 2;
    unsigned short* w1t_hi = (unsigned short*)p; p += (size_t)CC * FF * 2;
    unsigned short* w1t_lo = (unsigned short*)p; p += (size_t)CC * FF * 2;
    unsigned short* wvt_hi = (unsigned short*)p; p += (size_t)CC * FF * 2;
    unsigned short* wvt_lo = (unsigned short*)p; p += (size_t)CC * FF * 2;
    unsigned short* Wt_hi  = (unsigned short*)p; p += (size_t)HH * CC * CC * 2;
    unsigned short* Wt_lo  = (unsigned short*)p; p += (size_t)HH * CC * CC * 2;
    float* d4   = (float*)p;  p += (size_t)BB * CC * 4;
    float* e4   = (float*)p;  p += (size_t)HH * BB * CC * 4;
    float* atts = (float*)p;  p += (size_t)HH * BB * SS * 4;

    p_prep   <<<dim3(452),       256, 0, stream>>>(w1, wv, W, d1, b1,
                  w1t_hi, w1t_lo, wvt_hi, wvt_lo, Wt_hi, Wt_lo, d4, atts);
    k1_main  <<<dim3(1056),      256, 0, stream>>>(d2, w1t_hi, w1t_lo,
                  wvt_hi, wvt_lo, b1, d4, W, d3_hi, d3_lo, tv, e4);
    k3_atts  <<<dim3(512, HH),   256, 0, stream>>>(d3_hi, d3_lo, Wt_hi, Wt_lo,
                  e4, P, atts);
    k456_out <<<dim3(BB),        512, 0, stream>>>(atts, tv, wcc, bcc, out);
}